// Round 1
// baseline (251.556 us; speedup 1.0000x reference)
//
#include <hip/hip_runtime.h>
#include <stdint.h>

typedef unsigned short u16;
typedef __bf16 bf16x8 __attribute__((ext_vector_type(8)));
typedef float f32x4 __attribute__((ext_vector_type(4)));

// ---------- helpers ----------

__device__ __forceinline__ u16 f2bf(float f) {
    union { float f; uint32_t u; } c; c.f = f;
    return (u16)((c.u + 0x7fffu + ((c.u >> 16) & 1u)) >> 16);  // RNE
}

// async global->LDS, 16 bytes per lane; LDS dest = wave-uniform base + lane*16
__device__ __forceinline__ void g2lds16(const u16* g, u16* l) {
    __builtin_amdgcn_global_load_lds(
        (__attribute__((address_space(1))) void*)(void*)(g),
        (__attribute__((address_space(3))) void*)(l),
        16, 0, 0);
}

// ---------- f32 -> bf16 convert ----------

__global__ void cvt_f32_bf16(const float* __restrict__ in, u16* __restrict__ out, int n4) {
    int i = blockIdx.x * blockDim.x + threadIdx.x;
    int stride = gridDim.x * blockDim.x;
    for (; i < n4; i += stride) {
        float4 f = reinterpret_cast<const float4*>(in)[i];
        ushort4 u;
        u.x = f2bf(f.x); u.y = f2bf(f.y); u.z = f2bf(f.z); u.w = f2bf(f.w);
        reinterpret_cast<ushort4*>(out)[i] = u;
    }
}

// ---------- B^T GEMM: C[m][n] = scale * sum_k A[m][k] * B[n][k] ----------
// A: bf16 [M][lda], B: bf16 [N][ldb]. 128x128 tile, BK=32, 4 waves (2x2 of 64x64).
// OUT_MODE 0: bf16 C[m*ldc+n]; 1: bf16 transposed C[n*ldc+m]; 2: f32 scaled C[m*ldc+n].

template <int OUT_MODE>
__global__ __launch_bounds__(256)
void gemm_bt(const u16* __restrict__ A, const u16* __restrict__ B,
             void* __restrict__ Cv,
             int M, int N, int K, int lda, int ldb, int ldc,
             size_t strideA, size_t strideB, size_t strideC, float scale)
{
    A += (size_t)blockIdx.z * strideA;
    B += (size_t)blockIdx.z * strideB;

    const int tid  = threadIdx.x;
    const int wid  = tid >> 6;
    const int lane = tid & 63;
    const int wr = wid >> 1, wc = wid & 1;
    const int row0 = blockIdx.y * 128;
    const int col0 = blockIdx.x * 128;

    __shared__ __align__(16) u16 lA[128 * 32];
    __shared__ __align__(16) u16 lB[128 * 32];

    f32x4 acc[4][4] = {};

    // staging: wave wid covers tile rows [wid*32, wid*32+32) in two 16-row chunks
    const int srow = wid * 32 + (lane >> 2);   // + c*16
    const int scol = (lane & 3) * 8;
    const u16* gA = A + (size_t)(row0 + srow) * lda + scol;
    const u16* gB = B + (size_t)(col0 + srow) * ldb + scol;
    u16* sA = &lA[(wid * 32) * 32];
    u16* sB = &lB[(wid * 32) * 32];

    const int foff = (lane & 15) * 32 + (lane >> 4) * 8;  // fragment read offset

    for (int k0 = 0; k0 < K; k0 += 32) {
        __syncthreads();   // previous compute done reading LDS
        g2lds16(gA + k0,            sA);
        g2lds16(gA + k0 + 16 * lda, sA + 16 * 32);
        g2lds16(gB + k0,            sB);
        g2lds16(gB + k0 + 16 * ldb, sB + 16 * 32);
        __syncthreads();   // staging complete (compiler drains vmcnt before barrier)

        bf16x8 af[4], bv[4];
        #pragma unroll
        for (int m = 0; m < 4; ++m)
            af[m] = *reinterpret_cast<const bf16x8*>(&lA[(wr * 64 + m * 16) * 32 + foff]);
        #pragma unroll
        for (int n = 0; n < 4; ++n)
            bv[n] = *reinterpret_cast<const bf16x8*>(&lB[(wc * 64 + n * 16) * 32 + foff]);

        #pragma unroll
        for (int m = 0; m < 4; ++m)
            #pragma unroll
            for (int n = 0; n < 4; ++n)
                acc[m][n] = __builtin_amdgcn_mfma_f32_16x16x32_bf16(af[m], bv[n], acc[m][n], 0, 0, 0);
    }

    // epilogue: C/D layout col = lane&15, row = (lane>>4)*4 + j  [guide m89/m91]
    const int crow = row0 + wr * 64 + (lane >> 4) * 4;  // + m*16 + j
    const int ccol = col0 + wc * 64 + (lane & 15);      // + n*16

    if constexpr (OUT_MODE == 0) {
        u16* Cp = (u16*)Cv + (size_t)blockIdx.z * strideC;
        #pragma unroll
        for (int m = 0; m < 4; ++m)
            #pragma unroll
            for (int j = 0; j < 4; ++j) {
                size_t r = (size_t)(crow + m * 16 + j) * ldc;
                #pragma unroll
                for (int n = 0; n < 4; ++n)
                    Cp[r + ccol + n * 16] = f2bf(acc[m][n][j]);
            }
    } else if constexpr (OUT_MODE == 1) {
        u16* Cp = (u16*)Cv + (size_t)blockIdx.z * strideC;
        #pragma unroll
        for (int n = 0; n < 4; ++n) {
            size_t cbase = (size_t)(ccol + n * 16) * ldc;
            #pragma unroll
            for (int m = 0; m < 4; ++m) {
                ushort4 u;
                u.x = f2bf(acc[m][n][0]); u.y = f2bf(acc[m][n][1]);
                u.z = f2bf(acc[m][n][2]); u.w = f2bf(acc[m][n][3]);
                *reinterpret_cast<ushort4*>(&Cp[cbase + crow + m * 16]) = u;
            }
        }
    } else {
        float* Cp = (float*)Cv + (size_t)blockIdx.z * strideC;
        #pragma unroll
        for (int m = 0; m < 4; ++m)
            #pragma unroll
            for (int j = 0; j < 4; ++j) {
                size_t r = (size_t)(crow + m * 16 + j) * ldc;
                #pragma unroll
                for (int n = 0; n < 4; ++n)
                    Cp[r + ccol + n * 16] = acc[m][n][j] * scale;
            }
    }
}

// ---------- row softmax (2048 f32 -> 2048 bf16 in-place per row) ----------
// One block per row. Writes bf16 P over the FIRST 4KB of the row's own 8KB
// storage (same row only -> no cross-block hazard). P row stride = 4096 u16.

__global__ __launch_bounds__(256)
void softmax_bf16(float* __restrict__ scores) {
    const size_t row = blockIdx.x;
    float* rp = scores + row * 2048;
    const int tid = threadIdx.x;
    const int lane = tid & 63, wid = tid >> 6;

    float4 a = reinterpret_cast<const float4*>(rp)[tid * 2];
    float4 b = reinterpret_cast<const float4*>(rp)[tid * 2 + 1];
    float v[8] = { a.x, a.y, a.z, a.w, b.x, b.y, b.z, b.w };

    float mx = v[0];
    #pragma unroll
    for (int j = 1; j < 8; ++j) mx = fmaxf(mx, v[j]);
    #pragma unroll
    for (int off = 32; off >= 1; off >>= 1) mx = fmaxf(mx, __shfl_xor(mx, off));

    __shared__ float red_mx[4];
    __shared__ float red_s[4];
    if (lane == 0) red_mx[wid] = mx;
    __syncthreads();
    mx = fmaxf(fmaxf(red_mx[0], red_mx[1]), fmaxf(red_mx[2], red_mx[3]));

    float s = 0.f;
    #pragma unroll
    for (int j = 0; j < 8; ++j) { v[j] = __expf(v[j] - mx); s += v[j]; }
    #pragma unroll
    for (int off = 32; off >= 1; off >>= 1) s += __shfl_xor(s, off);
    if (lane == 0) red_s[wid] = s;
    __syncthreads();
    s = (red_s[0] + red_s[1]) + (red_s[2] + red_s[3]);
    float inv = 1.0f / s;

    u16* pw = (u16*)rp;
    ushort4 u0, u1;
    u0.x = f2bf(v[0] * inv); u0.y = f2bf(v[1] * inv);
    u0.z = f2bf(v[2] * inv); u0.w = f2bf(v[3] * inv);
    u1.x = f2bf(v[4] * inv); u1.y = f2bf(v[5] * inv);
    u1.z = f2bf(v[6] * inv); u1.w = f2bf(v[7] * inv);
    reinterpret_cast<ushort4*>(pw)[tid * 2]     = u0;
    reinterpret_cast<ushort4*>(pw)[tid * 2 + 1] = u1;
}

// ---------- launch ----------

extern "C" void kernel_launch(void* const* d_in, const int* in_sizes, int n_in,
                              void* d_out, int out_size, void* d_ws, size_t ws_size,
                              hipStream_t stream) {
    const float* x  = (const float*)d_in[0];
    const float* Wq = (const float*)d_in[1];
    const float* Wk = (const float*)d_in[2];
    const float* Wv = (const float*)d_in[3];

    const size_t SZ_X   = (size_t)8192 * 1024 * 2;   // 16 MB bf16
    const size_t SZ_W   = (size_t)1024 * 1024 * 2;   //  2 MB bf16
    const size_t SZ_SC  = (size_t)4 * 2048 * 2048 * 4; // 64 MB f32
    const size_t NEEDED = SZ_X * 4 /*xb,qb,kb,vT*/ + SZ_W * 3 + SZ_SC;
    if (ws_size < NEEDED) return;  // insufficient scratch: fail loudly (zeros)

    char* p = (char*)d_ws;
    u16* xb  = (u16*)p; p += SZ_X;
    u16* Wqb = (u16*)p; p += SZ_W;
    u16* Wkb = (u16*)p; p += SZ_W;
    u16* Wvb = (u16*)p; p += SZ_W;
    u16* qb  = (u16*)p; p += SZ_X;
    u16* kb  = (u16*)p; p += SZ_X;
    u16* vT  = (u16*)p; p += SZ_X;   // [1024][8192] bf16 (f-major, batches along s)
    float* sc = (float*)p;           // [4][2048][2048] f32

    // converts
    cvt_f32_bf16<<<2048, 256, 0, stream>>>(x,  xb,  8192 * 1024 / 4);
    cvt_f32_bf16<<<1024, 256, 0, stream>>>(Wq, Wqb, 1024 * 1024 / 4);
    cvt_f32_bf16<<<1024, 256, 0, stream>>>(Wk, Wkb, 1024 * 1024 / 4);
    cvt_f32_bf16<<<1024, 256, 0, stream>>>(Wv, Wvb, 1024 * 1024 / 4);

    dim3 blk(256);

    // q = x @ Wq^T, k = x @ Wk^T  (M=8192, N=1024, K=1024)
    gemm_bt<0><<<dim3(8, 64, 1), blk, 0, stream>>>(xb, Wqb, qb,
        8192, 1024, 1024, 1024, 1024, 1024, 0, 0, 0, 1.f);
    gemm_bt<0><<<dim3(8, 64, 1), blk, 0, stream>>>(xb, Wkb, kb,
        8192, 1024, 1024, 1024, 1024, 1024, 0, 0, 0, 1.f);
    // v, written transposed: vT[f][s_global]  (ldc = 8192)
    gemm_bt<1><<<dim3(8, 64, 1), blk, 0, stream>>>(xb, Wvb, vT,
        8192, 1024, 1024, 1024, 1024, 8192, 0, 0, 0, 1.f);

    // scores[b] = q_b @ k_b^T / 32  (M=N=2048, K=1024), f32
    gemm_bt<2><<<dim3(16, 16, 4), blk, 0, stream>>>(qb, kb, sc,
        2048, 2048, 1024, 1024, 1024, 2048,
        (size_t)2048 * 1024, (size_t)2048 * 1024, (size_t)2048 * 2048, 0.03125f);

    // softmax rows -> bf16 P in-place (P lda = 4096 u16)
    softmax_bf16<<<8192, 256, 0, stream>>>(sc);

    // out[b] = P_b @ vT_b^T  (M=2048, N=1024, K=2048), f32 -> d_out
    gemm_bt<2><<<dim3(8, 16, 4), blk, 0, stream>>>((const u16*)sc, vT, d_out,
        2048, 1024, 2048, 4096, 8192, 1024,
        (size_t)2048 * 4096, (size_t)2048, (size_t)2048 * 1024, 1.0f);
}

// Round 2
// 214.585 us; speedup vs baseline: 1.1723x; 1.1723x over previous
//
#include <hip/hip_runtime.h>
#include <stdint.h>

typedef unsigned short u16;
typedef __bf16 bf16x8 __attribute__((ext_vector_type(8)));
typedef float f32x4 __attribute__((ext_vector_type(4)));

__device__ __forceinline__ u16 f2bf(float f) {
    union { float f; uint32_t u; } c; c.f = f;
    return (u16)((c.u + 0x7fffu + ((c.u >> 16) & 1u)) >> 16);  // RNE
}

__device__ __forceinline__ void g2lds16(const u16* g, u16* l) {
    __builtin_amdgcn_global_load_lds(
        (__attribute__((address_space(1))) void*)(void*)(g),
        (__attribute__((address_space(3))) void*)(l),
        16, 0, 0);
}

// ---------- f32 -> bf16 convert ----------

__global__ void cvt_f32_bf16(const float* __restrict__ in, u16* __restrict__ out, int n4) {
    int i = blockIdx.x * blockDim.x + threadIdx.x;
    int st = gridDim.x * blockDim.x;
    for (; i < n4; i += st) {
        float4 f = reinterpret_cast<const float4*>(in)[i];
        ushort4 u{ f2bf(f.x), f2bf(f.y), f2bf(f.z), f2bf(f.w) };
        reinterpret_cast<ushort4*>(out)[i] = u;
    }
}

// ---------- 256x256 deep-pipelined B^T GEMM ----------
// C[m][n] = scale * sum_k A[m][k]*B[n][k].  BK=32, 4-slot LDS ring (128 KiB),
// 8 waves (2M x 4N), wave tile 128x64. Counted vmcnt (8/4/0), raw s_barrier,
// setprio around MFMA clusters. LDS layout per 16KB matrix-slot:
//   (row,k16) -> line=row>>1, ls=((row&1)*4+k16)^(line&7), u16off=line*64+ls*8
// Staging writes linearly (global_load_lds); per-thread source address applies
// the same involution, so ds_read with the swizzled address is conflict-free
// (2 lanes/bank). Verified by element trace.

template <int OUT_F32>
__global__ __launch_bounds__(512, 2)
void gemm256(const u16* __restrict__ A, const u16* __restrict__ B,
             void* __restrict__ Cv, int K, int lda, int ldb, int ldc,
             int bshift, size_t strideB, float scale)
{
    __shared__ __align__(16) u16 lds[4 * 16384];   // 4 slots x (A 16KB + B 16KB)

    const int tid  = threadIdx.x;
    const int wid  = tid >> 6, lane = tid & 63;
    const int wr = wid >> 2, wc = wid & 3;         // 2M x 4N waves
    const int row0 = blockIdx.y * 256;
    const int col0 = blockIdx.x * 256;
    const u16* Bb = B + (size_t)(row0 >> bshift) * strideB;

    // staging per-thread constants (2 calls of 512x16B per 16KB matrix-slot)
    int s_row[2], s_k[2], s_dst[2];
    #pragma unroll
    for (int c = 0; c < 2; ++c) {
        int p = c * 512 + tid;
        int line = p >> 3, ls = (p & 7) ^ (line & 7);
        s_row[c] = 2 * line + (ls >> 2);
        s_k[c]   = (ls & 3) * 8;
        s_dst[c] = (c * 512 + (tid & ~63)) * 8;    // wave-uniform base (u16)
    }

    auto stageA = [&](int T) {
        const int sb = (T & 3) * 16384, k0 = T * 32;
        #pragma unroll
        for (int c = 0; c < 2; ++c)
            g2lds16(A + (size_t)(row0 + s_row[c]) * lda + k0 + s_k[c],
                    &lds[sb + s_dst[c]]);
    };
    auto stageB = [&](int T) {
        const int sb = (T & 3) * 16384, k0 = T * 32;
        #pragma unroll
        for (int c = 0; c < 2; ++c)
            g2lds16(Bb + (size_t)(col0 + s_row[c]) * ldb + k0 + s_k[c],
                    &lds[sb + 8192 + s_dst[c]]);
    };

    // fragment read offsets (per-lane constant; conflict-free after swizzle)
    const int rl = lane & 15, kq = lane >> 4;
    const int ls = ((rl & 1) * 4 + kq) ^ ((rl >> 1) & 7);
    const int aoff = (wr * 64 + (rl >> 1)) * 64 + ls * 8;
    const int boff = 8192 + (wc * 32 + (rl >> 1)) * 64 + ls * 8;

    f32x4 acc[8][4] = {};
    bf16x8 afr[4], bfr[4];

    // prologue: stage tiles 0,1,2 (12 loads); wait tile 0 (leave 8 in flight)
    stageA(0); stageB(0); stageA(1); stageB(1); stageA(2); stageB(2);
    asm volatile("s_waitcnt vmcnt(8)" ::: "memory");
    __builtin_amdgcn_s_barrier();

    const int NT = K >> 5;
    for (int T = 0; T < NT; ++T) {
        const int sb = (T & 3) * 16384;

        // ---- phase 1: m-half 0 ----
        #pragma unroll
        for (int m = 0; m < 4; ++m) afr[m] = *(const bf16x8*)&lds[sb + aoff + m * 512];
        #pragma unroll
        for (int n = 0; n < 4; ++n) bfr[n] = *(const bf16x8*)&lds[sb + boff + n * 512];
        if (T + 3 < NT) stageA(T + 3);
        __builtin_amdgcn_s_barrier();
        asm volatile("s_waitcnt lgkmcnt(0)" ::: "memory");
        __builtin_amdgcn_sched_barrier(0);
        __builtin_amdgcn_s_setprio(1);
        #pragma unroll
        for (int m = 0; m < 4; ++m)
            #pragma unroll
            for (int n = 0; n < 4; ++n)
                acc[m][n] = __builtin_amdgcn_mfma_f32_16x16x32_bf16(afr[m], bfr[n], acc[m][n], 0, 0, 0);
        __builtin_amdgcn_s_setprio(0);
        __builtin_amdgcn_s_barrier();

        // ---- phase 2: m-half 1 (reuse B frags) ----
        #pragma unroll
        for (int m = 0; m < 4; ++m) afr[m] = *(const bf16x8*)&lds[sb + aoff + (m + 4) * 512];
        if (T + 3 < NT) stageB(T + 3);
        if (T < NT - 3)       { asm volatile("s_waitcnt vmcnt(8)" ::: "memory"); }
        else if (T == NT - 3) { asm volatile("s_waitcnt vmcnt(4)" ::: "memory"); }
        else if (T == NT - 2) { asm volatile("s_waitcnt vmcnt(0)" ::: "memory"); }
        __builtin_amdgcn_s_barrier();
        asm volatile("s_waitcnt lgkmcnt(0)" ::: "memory");
        __builtin_amdgcn_sched_barrier(0);
        __builtin_amdgcn_s_setprio(1);
        #pragma unroll
        for (int m = 0; m < 4; ++m)
            #pragma unroll
            for (int n = 0; n < 4; ++n)
                acc[m + 4][n] = __builtin_amdgcn_mfma_f32_16x16x32_bf16(afr[m], bfr[n], acc[m + 4][n], 0, 0, 0);
        __builtin_amdgcn_s_setprio(0);
        __builtin_amdgcn_s_barrier();
    }

    // epilogue: C/D layout col = lane&15, row = (lane>>4)*4 + j
    const int crow = row0 + wr * 128 + (lane >> 4) * 4;
    const int ccol = col0 + wc * 64 + (lane & 15);
    if constexpr (OUT_F32) {
        float* C = (float*)Cv;
        #pragma unroll
        for (int m = 0; m < 8; ++m)
            #pragma unroll
            for (int j = 0; j < 4; ++j) {
                size_t r = (size_t)(crow + m * 16 + j) * ldc;
                #pragma unroll
                for (int n = 0; n < 4; ++n)
                    C[r + ccol + n * 16] = acc[m][n][j] * scale;
            }
    } else {
        u16* C = (u16*)Cv;
        #pragma unroll
        for (int m = 0; m < 8; ++m)
            #pragma unroll
            for (int j = 0; j < 4; ++j) {
                size_t r = (size_t)(crow + m * 16 + j) * ldc;
                #pragma unroll
                for (int n = 0; n < 4; ++n)
                    C[r + ccol + n * 16] = f2bf(acc[m][n][j]);
            }
    }
}

// ---------- v-slice transpose: qkv cols [2048,3072) -> vT[1024][8192] ----------

__global__ __launch_bounds__(256)
void transpose_v(const u16* __restrict__ src, u16* __restrict__ dst) {
    __shared__ u16 t[64][72];
    const int tid = threadIdx.x;
    const int s0 = blockIdx.x * 64, f0 = blockIdx.y * 64;
    const int r = tid >> 3, c8 = (tid & 7) * 8;
    #pragma unroll
    for (int p = 0; p < 2; ++p) {
        const u16* s = &src[(size_t)(s0 + p * 32 + r) * 3072 + f0 + c8];
        ushort4 a = *(const ushort4*)s;
        ushort4 b = *(const ushort4*)(s + 4);
        *(ushort4*)&t[p * 32 + r][c8]     = a;
        *(ushort4*)&t[p * 32 + r][c8 + 4] = b;
    }
    __syncthreads();
    #pragma unroll
    for (int p = 0; p < 2; ++p) {
        int f = p * 32 + (tid >> 3);
        int sl = (tid & 7) * 8;
        ushort4 a{ t[sl + 0][f], t[sl + 1][f], t[sl + 2][f], t[sl + 3][f] };
        ushort4 b{ t[sl + 4][f], t[sl + 5][f], t[sl + 6][f], t[sl + 7][f] };
        u16* d = &dst[(size_t)(f0 + f) * 8192 + s0 + sl];
        *(ushort4*)d       = a;
        *(ushort4*)(d + 4) = b;
    }
}

// ---------- row softmax (2048 f32 -> 2048 bf16 in-place; P stride 4096 u16) ----------

__global__ __launch_bounds__(256)
void softmax_bf16(float* __restrict__ scores) {
    const size_t row = blockIdx.x;
    float* rp = scores + row * 2048;
    const int tid = threadIdx.x;
    const int lane = tid & 63, wid = tid >> 6;

    float4 a = reinterpret_cast<const float4*>(rp)[tid * 2];
    float4 b = reinterpret_cast<const float4*>(rp)[tid * 2 + 1];
    float v[8] = { a.x, a.y, a.z, a.w, b.x, b.y, b.z, b.w };

    float mx = v[0];
    #pragma unroll
    for (int j = 1; j < 8; ++j) mx = fmaxf(mx, v[j]);
    #pragma unroll
    for (int off = 32; off >= 1; off >>= 1) mx = fmaxf(mx, __shfl_xor(mx, off));

    __shared__ float red_mx[4], red_s[4];
    if (lane == 0) red_mx[wid] = mx;
    __syncthreads();
    mx = fmaxf(fmaxf(red_mx[0], red_mx[1]), fmaxf(red_mx[2], red_mx[3]));

    float s = 0.f;
    #pragma unroll
    for (int j = 0; j < 8; ++j) { v[j] = __expf(v[j] - mx); s += v[j]; }
    #pragma unroll
    for (int off = 32; off >= 1; off >>= 1) s += __shfl_xor(s, off);
    if (lane == 0) red_s[wid] = s;
    __syncthreads();
    s = (red_s[0] + red_s[1]) + (red_s[2] + red_s[3]);
    float inv = 1.0f / s;

    u16* pw = (u16*)rp;
    ushort4 u0{ f2bf(v[0] * inv), f2bf(v[1] * inv), f2bf(v[2] * inv), f2bf(v[3] * inv) };
    ushort4 u1{ f2bf(v[4] * inv), f2bf(v[5] * inv), f2bf(v[6] * inv), f2bf(v[7] * inv) };
    reinterpret_cast<ushort4*>(pw)[tid * 2]     = u0;
    reinterpret_cast<ushort4*>(pw)[tid * 2 + 1] = u1;
}

// ---------- launch ----------

extern "C" void kernel_launch(void* const* d_in, const int* in_sizes, int n_in,
                              void* d_out, int out_size, void* d_ws, size_t ws_size,
                              hipStream_t stream) {
    const float* x  = (const float*)d_in[0];
    const float* Wq = (const float*)d_in[1];
    const float* Wk = (const float*)d_in[2];
    const float* Wv = (const float*)d_in[3];

    // ws layout (MiB): [0,64) sc f32 | [0,16) xb | [16,22) Wqkv (both dead
    // before sc is written) | [64,112) qkv bf16 | [112,128) vT
    const size_t MiB = 1024 * 1024;
    if (ws_size < 128 * MiB) return;
    char* base = (char*)d_ws;
    float* sc   = (float*)base;
    u16*  xb    = (u16*)base;
    u16*  Wqkvb = (u16*)(base + 16 * MiB);
    u16*  qkvb  = (u16*)(base + 64 * MiB);
    u16*  vT    = (u16*)(base + 112 * MiB);

    cvt_f32_bf16<<<2048, 256, 0, stream>>>(x,  xb, 8192 * 1024 / 4);
    cvt_f32_bf16<<<1024, 256, 0, stream>>>(Wq, Wqkvb,               1024 * 1024 / 4);
    cvt_f32_bf16<<<1024, 256, 0, stream>>>(Wk, Wqkvb + 1024 * 1024, 1024 * 1024 / 4);
    cvt_f32_bf16<<<1024, 256, 0, stream>>>(Wv, Wqkvb + 2048 * 1024, 1024 * 1024 / 4);

    // qkv = x @ Wqkv^T : M=8192, N=3072, K=1024 -> bf16 qkvb[8192][3072]
    gemm256<0><<<dim3(12, 32), 512, 0, stream>>>(xb, Wqkvb, qkvb,
        1024, 1024, 1024, 3072, 31, 0, 1.0f);

    // vT[f][s_global] from qkv v-slice
    transpose_v<<<dim3(128, 16), 256, 0, stream>>>(qkvb + 2048, vT);

    // scores = q @ k^T / 32 : M=8192(global s), N=2048, K=1024 -> f32 sc[8192][2048]
    gemm256<1><<<dim3(8, 32), 512, 0, stream>>>(qkvb, qkvb + 1024, sc,
        1024, 3072, 3072, 2048, 11, (size_t)2048 * 3072, 0.03125f);

    // softmax rows -> bf16 P in place (lda 4096 u16)
    softmax_bf16<<<8192, 256, 0, stream>>>(sc);

    // out = P @ vT^T : M=8192, N=1024, K=2048 -> f32 d_out[8192][1024]
    gemm256<1><<<dim3(4, 32), 512, 0, stream>>>((const u16*)sc, vT, d_out,
        2048, 4096, 8192, 1024, 11, 2048, 1.0f);
}

// Round 4
// 190.278 us; speedup vs baseline: 1.3220x; 1.1277x over previous
//
#include <hip/hip_runtime.h>
#include <stdint.h>

typedef unsigned short u16;
typedef uint32_t u32;
typedef __bf16 bf16x8 __attribute__((ext_vector_type(8)));
typedef float f32x4 __attribute__((ext_vector_type(4)));
typedef uint32_t u32x4 __attribute__((ext_vector_type(4)));

__device__ __forceinline__ u16 f2bf(float f) {
    union { float f; uint32_t u; } c; c.f = f;
    return (u16)((c.u + 0x7fffu + ((c.u >> 16) & 1u)) >> 16);  // RNE
}

__device__ __forceinline__ void g2lds16(const u16* g, u16* l) {
    __builtin_amdgcn_global_load_lds(
        (__attribute__((address_space(1))) void*)(void*)(g),
        (__attribute__((address_space(3))) void*)(l),
        16, 0, 0);
}

template <int N> __device__ __forceinline__ void waitcnt_vm() {
    if constexpr      (N == 8) asm volatile("s_waitcnt vmcnt(8)" ::: "memory");
    else if constexpr (N == 6) asm volatile("s_waitcnt vmcnt(6)" ::: "memory");
    else if constexpr (N == 4) asm volatile("s_waitcnt vmcnt(4)" ::: "memory");
    else if constexpr (N == 3) asm volatile("s_waitcnt vmcnt(3)" ::: "memory");
    else                       asm volatile("s_waitcnt vmcnt(0)" ::: "memory");
}

// ---------- fused f32 -> bf16 convert (x, Wq, Wk, Wv in one launch) ----------

__global__ __launch_bounds__(256)
void cvt_all(const float* __restrict__ x, const float* __restrict__ wq,
             const float* __restrict__ wk, const float* __restrict__ wv,
             u16* __restrict__ xb, u16* __restrict__ wb) {
    const int b = blockIdx.x, tid = threadIdx.x;
    const float* src; u16* dst; int off;
    if (b < 2048) { src = x; dst = xb; off = b * 1024; }
    else {
        int w = (b - 2048) >> 8;
        src = (w == 0) ? wq : (w == 1) ? wk : wv;
        dst = wb + (size_t)w * 1048576;
        off = ((b - 2048) & 255) * 1024;
    }
    #pragma unroll
    for (int k2 = 0; k2 < 4; ++k2) {
        int i = off + k2 * 256 + tid;
        float4 f = reinterpret_cast<const float4*>(src)[i];
        ushort4 u{ f2bf(f.x), f2bf(f.y), f2bf(f.z), f2bf(f.w) };
        reinterpret_cast<ushort4*>(dst)[i] = u;
    }
}

// ---------- 256xBN deep-pipelined B^T GEMM ----------
// C[m][n] = scale * sum_k A[m][k]*B[n][k].  BK=32, 4-slot LDS ring, 8 waves.
// NWC=4: BN=256, waves 2Mx4N (wave tile 128x64), 128KB LDS, L=4 loads/tile.
// NWC=2: BN=128, waves 4Mx2N (wave tile  64x64),  96KB LDS, L=3 loads/tile.
// Counted vmcnt (2L steady / L / 0 tail), raw s_barrier, setprio on MFMA.
// MODE 0 (qkv): col0<2048 -> bf16 row-major to qk (LDS-staged, coalesced);
//               col0>=2048 -> transposed bf16 write to vT[1024][8192].
// MODE 1: f32 * scale direct store.

template <int MODE, int NWC>
__global__ __launch_bounds__(512, 2)
void gemm256(const u16* __restrict__ A, const u16* __restrict__ B,
             void* __restrict__ Cv, u16* __restrict__ vTp,
             int K, int lda, int ldb, int ldc,
             int bshift, size_t strideB, float scale)
{
    constexpr int MACC = (NWC == 4) ? 8 : 4;   // A-frag repeats per wave
    constexpr int PH   = MACC / 2;             // per phase
    constexpr int SLOT = 8192 + 2048 * NWC;    // u16 per ring slot
    constexpr int SBC  = NWC / 2;              // B stage calls per tile
    constexpr int L    = 2 + SBC;              // loads per tile

    __shared__ __align__(16) u16 lds[4 * SLOT];

    const int tid  = threadIdx.x;
    const int wid  = tid >> 6, lane = tid & 63;
    const int wr = wid / NWC, wc = wid % NWC;
    const int row0 = blockIdx.y * 256;
    const int col0 = blockIdx.x * (64 * NWC);
    const u16* Bb = B + (size_t)(row0 >> bshift) * strideB;

    // staging per-thread constants (each call: 512 lanes x 16B = 8KB)
    int s_row[2], s_k[2], s_dst[2];
    #pragma unroll
    for (int c = 0; c < 2; ++c) {
        int p = c * 512 + tid;
        int line = p >> 3, ls = (p & 7) ^ (line & 7);
        s_row[c] = 2 * line + (ls >> 2);
        s_k[c]   = (ls & 3) * 8;
        s_dst[c] = (c * 512 + (tid & ~63)) * 8;
    }

    auto stageA = [&](int T) {
        const int sb = (T & 3) * SLOT, k0 = T * 32;
        #pragma unroll
        for (int c = 0; c < 2; ++c)
            g2lds16(A + (size_t)(row0 + s_row[c]) * lda + k0 + s_k[c],
                    &lds[sb + s_dst[c]]);
    };
    auto stageB = [&](int T) {
        const int sb = (T & 3) * SLOT, k0 = T * 32;
        #pragma unroll
        for (int c = 0; c < SBC; ++c)
            g2lds16(Bb + (size_t)(col0 + s_row[c]) * ldb + k0 + s_k[c],
                    &lds[sb + 8192 + s_dst[c]]);
    };

    const int rl = lane & 15, kq = lane >> 4;
    const int ls2  = ((rl & 1) * 4 + kq) ^ ((rl >> 1) & 7);
    const int aoff = (wr * (MACC * 8) + (rl >> 1)) * 64 + ls2 * 8;
    const int boff = 8192 + (wc * 32 + (rl >> 1)) * 64 + ls2 * 8;

    f32x4 acc[MACC][4] = {};
    bf16x8 afr[PH], bfr[4];

    stageA(0); stageB(0); stageA(1); stageB(1); stageA(2); stageB(2);
    waitcnt_vm<2 * L>();
    __builtin_amdgcn_s_barrier();

    const int NT = K >> 5;
    for (int T = 0; T < NT; ++T) {
        const int sb = (T & 3) * SLOT;

        // ---- phase 1 ----
        #pragma unroll
        for (int m = 0; m < PH; ++m) afr[m] = *(const bf16x8*)&lds[sb + aoff + m * 512];
        #pragma unroll
        for (int n = 0; n < 4; ++n)  bfr[n] = *(const bf16x8*)&lds[sb + boff + n * 512];
        if (T + 3 < NT) stageA(T + 3);
        __builtin_amdgcn_s_barrier();
        asm volatile("s_waitcnt lgkmcnt(0)" ::: "memory");
        __builtin_amdgcn_sched_barrier(0);
        __builtin_amdgcn_s_setprio(1);
        #pragma unroll
        for (int m = 0; m < PH; ++m)
            #pragma unroll
            for (int n = 0; n < 4; ++n)
                acc[m][n] = __builtin_amdgcn_mfma_f32_16x16x32_bf16(afr[m], bfr[n], acc[m][n], 0, 0, 0);
        __builtin_amdgcn_s_setprio(0);
        __builtin_amdgcn_s_barrier();

        // ---- phase 2 ----
        #pragma unroll
        for (int m = 0; m < PH; ++m) afr[m] = *(const bf16x8*)&lds[sb + aoff + (m + PH) * 512];
        if (T + 3 < NT) stageB(T + 3);
        if (T < NT - 3)       waitcnt_vm<2 * L>();
        else if (T == NT - 3) waitcnt_vm<L>();
        else if (T == NT - 2) waitcnt_vm<0>();
        __builtin_amdgcn_s_barrier();
        asm volatile("s_waitcnt lgkmcnt(0)" ::: "memory");
        __builtin_amdgcn_sched_barrier(0);
        __builtin_amdgcn_s_setprio(1);
        #pragma unroll
        for (int m = 0; m < PH; ++m)
            #pragma unroll
            for (int n = 0; n < 4; ++n)
                acc[m + PH][n] = __builtin_amdgcn_mfma_f32_16x16x32_bf16(afr[m], bfr[n], acc[m + PH][n], 0, 0, 0);
        __builtin_amdgcn_s_setprio(0);
        __builtin_amdgcn_s_barrier();
    }

    // ---------- epilogue ----------
    // C/D frag: col = col0 + wc*64 + n*16 + rl ; row = row0 + wr*MACC*16 + m*16 + kq*4 + j
    const int kq4 = kq * 4;

    if constexpr (MODE == 1) {
        float* C = (float*)Cv;
        #pragma unroll
        for (int m = 0; m < MACC; ++m)
            #pragma unroll
            for (int j = 0; j < 4; ++j) {
                size_t r = (size_t)(row0 + wr * (MACC * 16) + m * 16 + kq4 + j) * ldc;
                #pragma unroll
                for (int n = 0; n < 4; ++n)
                    C[r + col0 + wc * 64 + n * 16 + rl] = acc[m][n][j] * scale;
            }
    } else if (col0 < 2048) {
        // q/k: stage per-wave 64x64 f32 halves in own LDS region, store coalesced bf16
        float* tw = (float*)&lds[(size_t)wid * 8192];   // [64 rows][64 cols] swizzled
        u16* Cq = (u16*)Cv;
        #pragma unroll
        for (int h = 0; h < 2; ++h) {
            #pragma unroll
            for (int mm = 0; mm < 4; ++mm)
                #pragma unroll
                for (int n = 0; n < 4; ++n)
                    #pragma unroll
                    for (int j = 0; j < 4; ++j) {
                        int rowl = mm * 16 + kq4 + j;
                        int c2 = (rl + n * 16) ^ ((((rowl) >> 2) & 3) << 4);
                        tw[rowl * 64 + c2] = acc[h * 4 + mm][n][j];
                    }
            #pragma unroll
            for (int it = 0; it < 16; ++it) {
                int rowr = it * 4 + kq;
                int c2 = (rl * 4) ^ ((it & 3) << 4);
                f32x4 v4 = *(const f32x4*)&tw[rowr * 64 + c2];
                ushort4 u{ f2bf(v4[0]), f2bf(v4[1]), f2bf(v4[2]), f2bf(v4[3]) };
                *(ushort4*)&Cq[(size_t)(row0 + wr * 128 + h * 64 + rowr) * ldc
                               + col0 + wc * 64 + rl * 4] = u;
            }
        }
    } else {
        // v: stage transposed (packed s-pairs), write vT[f][s] coalesced along s
        u32* tv = (u32*)&lds[(size_t)wid * 8192];       // [64 f][64 s2] swizzled
        const int s0  = row0 + wr * 128;
        const int f0v = col0 - 2048 + wc * 64;
        #pragma unroll
        for (int m = 0; m < 8; ++m)
            #pragma unroll
            for (int n = 0; n < 4; ++n)
                #pragma unroll
                for (int j2 = 0; j2 < 2; ++j2) {
                    int fl = rl + n * 16;
                    int s2 = m * 8 + kq * 2 + j2;
                    u32 pk = (u32)f2bf(acc[m][n][j2 * 2])
                           | ((u32)f2bf(acc[m][n][j2 * 2 + 1]) << 16);
                    tv[fl * 64 + (s2 ^ ((fl & 15) << 2))] = pk;
                }
        // read/store: 16 iterations cover all 64 f-rows x 64 s2-pairs
        // (r3 bug: it<8 with ck=lane&7 covered only s2<32 -> half of vT unwritten)
        #pragma unroll
        for (int it = 0; it < 16; ++it) {
            int fr = it * 4 + (lane >> 4);
            int ck = lane & 15;
            int s2s = (ck * 4) ^ ((fr & 15) << 2);
            u32x4 v4 = *(const u32x4*)&tv[fr * 64 + s2s];
            *(u32x4*)&vTp[(size_t)(f0v + fr) * 8192 + s0 + ck * 8] = v4;
        }
    }
}

// ---------- row softmax (2048 f32 -> 2048 bf16 in-place; P stride 4096 u16) ----------

__global__ __launch_bounds__(256)
void softmax_bf16(float* __restrict__ scores) {
    const size_t row = blockIdx.x;
    float* rp = scores + row * 2048;
    const int tid = threadIdx.x;
    const int lane = tid & 63, wid = tid >> 6;

    float4 a = reinterpret_cast<const float4*>(rp)[tid * 2];
    float4 b = reinterpret_cast<const float4*>(rp)[tid * 2 + 1];
    float v[8] = { a.x, a.y, a.z, a.w, b.x, b.y, b.z, b.w };

    float mx = v[0];
    #pragma unroll
    for (int j = 1; j < 8; ++j) mx = fmaxf(mx, v[j]);
    #pragma unroll
    for (int off = 32; off >= 1; off >>= 1) mx = fmaxf(mx, __shfl_xor(mx, off));

    __shared__ float red_mx[4], red_s[4];
    if (lane == 0) red_mx[wid] = mx;
    __syncthreads();
    mx = fmaxf(fmaxf(red_mx[0], red_mx[1]), fmaxf(red_mx[2], red_mx[3]));

    float s = 0.f;
    #pragma unroll
    for (int j = 0; j < 8; ++j) { v[j] = __expf(v[j] - mx); s += v[j]; }
    #pragma unroll
    for (int off = 32; off >= 1; off >>= 1) s += __shfl_xor(s, off);
    if (lane == 0) red_s[wid] = s;
    __syncthreads();
    s = (red_s[0] + red_s[1]) + (red_s[2] + red_s[3]);
    float inv = 1.0f / s;

    u16* pw = (u16*)rp;
    ushort4 u0{ f2bf(v[0] * inv), f2bf(v[1] * inv), f2bf(v[2] * inv), f2bf(v[3] * inv) };
    ushort4 u1{ f2bf(v[4] * inv), f2bf(v[5] * inv), f2bf(v[6] * inv), f2bf(v[7] * inv) };
    reinterpret_cast<ushort4*>(pw)[tid * 2]     = u0;
    reinterpret_cast<ushort4*>(pw)[tid * 2 + 1] = u1;
}

// ---------- launch ----------

extern "C" void kernel_launch(void* const* d_in, const int* in_sizes, int n_in,
                              void* d_out, int out_size, void* d_ws, size_t ws_size,
                              hipStream_t stream) {
    const float* x  = (const float*)d_in[0];
    const float* Wq = (const float*)d_in[1];
    const float* Wk = (const float*)d_in[2];
    const float* Wv = (const float*)d_in[3];

    // ws (MiB): [0,64) sc f32 | aliased: [0,16) xb, [16,22) Wqkv (dead before
    // sc written) | [64,96) qk bf16 [8192][2048] | [96,112) vT bf16 [1024][8192]
    const size_t MiB = 1024 * 1024;
    if (ws_size < 112 * MiB) return;
    char* base = (char*)d_ws;
    float* sc   = (float*)base;
    u16*  xb    = (u16*)base;
    u16*  Wqkvb = (u16*)(base + 16 * MiB);
    u16*  qkb   = (u16*)(base + 64 * MiB);
    u16*  vT    = (u16*)(base + 96 * MiB);

    cvt_all<<<2816, 256, 0, stream>>>(x, Wq, Wk, Wv, xb, Wqkvb);

    // qkv = x @ Wqkv^T : M=8192, N=3072, K=1024 -> q,k into qkb; v into vT
    gemm256<0, 4><<<dim3(12, 32), 512, 0, stream>>>(xb, Wqkvb, qkb, vT,
        1024, 1024, 1024, 2048, 31, 0, 1.0f);

    // scores = q @ k^T / 32 : M=8192, N=2048, K=1024 -> f32 sc
    gemm256<1, 4><<<dim3(8, 32), 512, 0, stream>>>(qkb, qkb + 1024, sc, nullptr,
        1024, 2048, 2048, 2048, 11, (size_t)2048 * 2048, 0.03125f);

    // softmax rows -> bf16 P in place (lda 4096 u16)
    softmax_bf16<<<8192, 256, 0, stream>>>(sc);

    // out = P @ vT^T : M=8192, N=1024(f), K=2048(s) -> f32 d_out
    gemm256<1, 2><<<dim3(8, 32), 512, 0, stream>>>((const u16*)sc, vT, d_out, nullptr,
        2048, 4096, 8192, 1024, 11, 2048, 1.0f);
}

// Round 6
// 186.207 us; speedup vs baseline: 1.3510x; 1.0219x over previous
//
#include <hip/hip_runtime.h>
#include <stdint.h>

typedef unsigned short u16;
typedef uint32_t u32;
typedef __bf16 bf16x8 __attribute__((ext_vector_type(8)));
typedef float f32x4 __attribute__((ext_vector_type(4)));
typedef uint32_t u32x4 __attribute__((ext_vector_type(4)));

__device__ __forceinline__ u16 f2bf(float f) {
    union { float f; uint32_t u; } c; c.f = f;
    return (u16)((c.u + 0x7fffu + ((c.u >> 16) & 1u)) >> 16);  // RNE
}

__device__ __forceinline__ void g2lds16(const u16* g, u16* l) {
    __builtin_amdgcn_global_load_lds(
        (__attribute__((address_space(1))) void*)(void*)(g),
        (__attribute__((address_space(3))) void*)(l),
        16, 0, 0);
}

template <int N> __device__ __forceinline__ void waitcnt_vm() {
    if constexpr      (N == 8) asm volatile("s_waitcnt vmcnt(8)" ::: "memory");
    else if constexpr (N == 6) asm volatile("s_waitcnt vmcnt(6)" ::: "memory");
    else if constexpr (N == 4) asm volatile("s_waitcnt vmcnt(4)" ::: "memory");
    else if constexpr (N == 3) asm volatile("s_waitcnt vmcnt(3)" ::: "memory");
    else                       asm volatile("s_waitcnt vmcnt(0)" ::: "memory");
}

// ---------- fused f32 -> bf16 convert (x, Wq, Wk, Wv in one launch) ----------

__global__ __launch_bounds__(256)
void cvt_all(const float* __restrict__ x, const float* __restrict__ wq,
             const float* __restrict__ wk, const float* __restrict__ wv,
             u16* __restrict__ xb, u16* __restrict__ wb) {
    const int b = blockIdx.x, tid = threadIdx.x;
    const float* src; u16* dst; int off;
    if (b < 2048) { src = x; dst = xb; off = b * 1024; }
    else {
        int w = (b - 2048) >> 8;
        src = (w == 0) ? wq : (w == 1) ? wk : wv;
        dst = wb + (size_t)w * 1048576;
        off = ((b - 2048) & 255) * 1024;
    }
    #pragma unroll
    for (int k2 = 0; k2 < 4; ++k2) {
        int i = off + k2 * 256 + tid;
        float4 f = reinterpret_cast<const float4*>(src)[i];
        ushort4 u{ f2bf(f.x), f2bf(f.y), f2bf(f.z), f2bf(f.w) };
        reinterpret_cast<ushort4*>(dst)[i] = u;
    }
}

// ---------- 256xBN deep-pipelined B^T GEMM ----------
// C[m][n] = scale * sum_k A[m][k]*B[n][k].  BK=32, 4-slot LDS ring, 8 waves.
// NWC=4: BN=256, waves 2Mx4N (wave tile 128x64), 128KB LDS, L=4 loads/tile.
// NWC=2: BN=128, waves 4Mx2N (wave tile  64x64),  96KB LDS, L=3 loads/tile.
// MODE 0: bf16 row-major via LDS-staged coalesced store (NWC=4; r4-verified).
// MODE 1: f32*scale direct store (r4-verified).
// MODE 3: bf16 transposed store to vT[1024][8192] (NWC=2; r5 code under test).

template <int MODE, int NWC>
__global__ __launch_bounds__(512, 2)
void gemm256(const u16* __restrict__ A, const u16* __restrict__ B,
             void* __restrict__ Cv, u16* __restrict__ vTp,
             int K, int lda, int ldb, int ldc,
             int bshift, size_t strideB, float scale)
{
    constexpr int MACC = (NWC == 4) ? 8 : 4;   // A-frag repeats per wave
    constexpr int PH   = MACC / 2;             // per phase
    constexpr int SLOT = 8192 + 2048 * NWC;    // u16 per ring slot
    constexpr int SBC  = NWC / 2;              // B stage calls per tile
    constexpr int L    = 2 + SBC;              // loads per tile

    __shared__ __align__(16) u16 lds[4 * SLOT];

    const int tid  = threadIdx.x;
    const int wid  = tid >> 6, lane = tid & 63;
    const int wr = wid / NWC, wc = wid % NWC;
    const int row0 = blockIdx.y * 256;
    const int col0 = blockIdx.x * (64 * NWC);
    const u16* Bb = B + (size_t)(row0 >> bshift) * strideB;

    // staging per-thread constants (each call: 512 lanes x 16B = 8KB)
    int s_row[2], s_k[2], s_dst[2];
    #pragma unroll
    for (int c = 0; c < 2; ++c) {
        int p = c * 512 + tid;
        int line = p >> 3, ls = (p & 7) ^ (line & 7);
        s_row[c] = 2 * line + (ls >> 2);
        s_k[c]   = (ls & 3) * 8;
        s_dst[c] = (c * 512 + (tid & ~63)) * 8;
    }

    auto stageA = [&](int T) {
        const int sb = (T & 3) * SLOT, k0 = T * 32;
        #pragma unroll
        for (int c = 0; c < 2; ++c)
            g2lds16(A + (size_t)(row0 + s_row[c]) * lda + k0 + s_k[c],
                    &lds[sb + s_dst[c]]);
    };
    auto stageB = [&](int T) {
        const int sb = (T & 3) * SLOT, k0 = T * 32;
        #pragma unroll
        for (int c = 0; c < SBC; ++c)
            g2lds16(Bb + (size_t)(col0 + s_row[c]) * ldb + k0 + s_k[c],
                    &lds[sb + 8192 + s_dst[c]]);
    };

    const int rl = lane & 15, kq = lane >> 4;
    const int ls2  = ((rl & 1) * 4 + kq) ^ ((rl >> 1) & 7);
    const int aoff = (wr * (MACC * 8) + (rl >> 1)) * 64 + ls2 * 8;
    const int boff = 8192 + (wc * 32 + (rl >> 1)) * 64 + ls2 * 8;

    f32x4 acc[MACC][4] = {};
    bf16x8 afr[PH], bfr[4];

    stageA(0); stageB(0); stageA(1); stageB(1); stageA(2); stageB(2);
    waitcnt_vm<2 * L>();
    __builtin_amdgcn_s_barrier();

    const int NT = K >> 5;
    for (int T = 0; T < NT; ++T) {
        const int sb = (T & 3) * SLOT;

        // ---- phase 1 ----
        #pragma unroll
        for (int m = 0; m < PH; ++m) afr[m] = *(const bf16x8*)&lds[sb + aoff + m * 512];
        #pragma unroll
        for (int n = 0; n < 4; ++n)  bfr[n] = *(const bf16x8*)&lds[sb + boff + n * 512];
        if (T + 3 < NT) stageA(T + 3);
        __builtin_amdgcn_s_barrier();
        asm volatile("s_waitcnt lgkmcnt(0)" ::: "memory");
        __builtin_amdgcn_sched_barrier(0);
        __builtin_amdgcn_s_setprio(1);
        #pragma unroll
        for (int m = 0; m < PH; ++m)
            #pragma unroll
            for (int n = 0; n < 4; ++n)
                acc[m][n] = __builtin_amdgcn_mfma_f32_16x16x32_bf16(afr[m], bfr[n], acc[m][n], 0, 0, 0);
        __builtin_amdgcn_s_setprio(0);
        __builtin_amdgcn_s_barrier();

        // ---- phase 2 ----
        #pragma unroll
        for (int m = 0; m < PH; ++m) afr[m] = *(const bf16x8*)&lds[sb + aoff + (m + PH) * 512];
        if (T + 3 < NT) stageB(T + 3);
        if (T < NT - 3)       waitcnt_vm<2 * L>();
        else if (T == NT - 3) waitcnt_vm<L>();
        else if (T == NT - 2) waitcnt_vm<0>();
        __builtin_amdgcn_s_barrier();
        asm volatile("s_waitcnt lgkmcnt(0)" ::: "memory");
        __builtin_amdgcn_sched_barrier(0);
        __builtin_amdgcn_s_setprio(1);
        #pragma unroll
        for (int m = 0; m < PH; ++m)
            #pragma unroll
            for (int n = 0; n < 4; ++n)
                acc[m + PH][n] = __builtin_amdgcn_mfma_f32_16x16x32_bf16(afr[m], bfr[n], acc[m + PH][n], 0, 0, 0);
        __builtin_amdgcn_s_setprio(0);
        __builtin_amdgcn_s_barrier();
    }

    // ---------- epilogue ----------
    // C/D frag: col = col0 + wc*64 + n*16 + rl ; row = row0 + wr*MACC*16 + m*16 + kq*4 + j
    const int kq4 = kq * 4;

    if constexpr (MODE == 1) {
        float* C = (float*)Cv;
        #pragma unroll
        for (int m = 0; m < MACC; ++m)
            #pragma unroll
            for (int j = 0; j < 4; ++j) {
                size_t r = (size_t)(row0 + wr * (MACC * 16) + m * 16 + kq4 + j) * ldc;
                #pragma unroll
                for (int n = 0; n < 4; ++n)
                    C[r + col0 + wc * 64 + n * 16 + rl] = acc[m][n][j] * scale;
            }
    } else if constexpr (MODE == 0) {
        // bf16: stage per-wave 64x64 f32 tiles in own LDS region, store coalesced
        float* tw = (float*)&lds[(size_t)wid * 8192];   // [64 rows][64 cols] swizzled
        u16* Cq = (u16*)Cv;
        #pragma unroll
        for (int h = 0; h < MACC / 4; ++h) {
            #pragma unroll
            for (int mm = 0; mm < 4; ++mm)
                #pragma unroll
                for (int n = 0; n < 4; ++n)
                    #pragma unroll
                    for (int j = 0; j < 4; ++j) {
                        int rowl = mm * 16 + kq4 + j;
                        int c2 = (rl + n * 16) ^ ((((rowl) >> 2) & 3) << 4);
                        tw[rowl * 64 + c2] = acc[h * 4 + mm][n][j];
                    }
            #pragma unroll
            for (int it = 0; it < 16; ++it) {
                int rowr = it * 4 + kq;
                int c2 = (rl * 4) ^ ((it & 3) << 4);
                f32x4 v4 = *(const f32x4*)&tw[rowr * 64 + c2];
                ushort4 u{ f2bf(v4[0]), f2bf(v4[1]), f2bf(v4[2]), f2bf(v4[3]) };
                *(ushort4*)&Cq[(size_t)(row0 + wr * (MACC * 16) + h * 64 + rowr) * ldc
                               + col0 + wc * 64 + rl * 4] = u;
            }
        }
    } else {
        // MODE 3 (NWC=2): transposed bf16 store, wave tile 64(s) x 64(f) -> vT[f][s]
        u32* tv = (u32*)&lds[(size_t)wid * 4096];       // [64 f][32 s2] swizzled (8KB)
        const int s0  = row0 + wr * 64;
        const int f0v = col0 + wc * 64;
        #pragma unroll
        for (int m = 0; m < 4; ++m)
            #pragma unroll
            for (int n = 0; n < 4; ++n)
                #pragma unroll
                for (int j2 = 0; j2 < 2; ++j2) {
                    int fl = rl + n * 16;
                    int s2 = m * 8 + kq * 2 + j2;
                    u32 pk = (u32)f2bf(acc[m][n][j2 * 2])
                           | ((u32)f2bf(acc[m][n][j2 * 2 + 1]) << 16);
                    tv[fl * 32 + (s2 ^ ((fl & 7) << 2))] = pk;
                }
        #pragma unroll
        for (int it = 0; it < 8; ++it) {
            int fr = it * 8 + (lane >> 3);
            int ck = lane & 7;
            int s2s = (ck * 4) ^ ((fr & 7) << 2);
            u32x4 v4 = *(const u32x4*)&tv[fr * 32 + s2s];
            *(u32x4*)&vTp[(size_t)(f0v + fr) * 8192 + s0 + ck * 8] = v4;
        }
    }
}

// ---------- row softmax (2048 f32 -> 2048 bf16 in-place per row) ----------
// One block per row. Writes bf16 P over the FIRST 4KB of the row's own 8KB
// storage (same row only -> no cross-block hazard). P row stride = 4096 u16.

__global__ __launch_bounds__(256)
void softmax_bf16(float* __restrict__ scores) {
    const size_t row = blockIdx.x;
    float* rp = scores + row * 2048;
    const int tid = threadIdx.x;
    const int lane = tid & 63, wid = tid >> 6;

    float4 a = reinterpret_cast<const float4*>(rp)[tid * 2];
    float4 b = reinterpret_cast<const float4*>(rp)[tid * 2 + 1];
    float v[8] = { a.x, a.y, a.z, a.w, b.x, b.y, b.z, b.w };

    float mx = v[0];
    #pragma unroll
    for (int j = 1; j < 8; ++j) mx = fmaxf(mx, v[j]);
    #pragma unroll
    for (int off = 32; off >= 1; off >>= 1) mx = fmaxf(mx, __shfl_xor(mx, off));

    __shared__ float red_mx[4], red_s[4];
    if (lane == 0) red_mx[wid] = mx;
    __syncthreads();
    mx = fmaxf(fmaxf(red_mx[0], red_mx[1]), fmaxf(red_mx[2], red_mx[3]));

    float s = 0.f;
    #pragma unroll
    for (int j = 0; j < 8; ++j) { v[j] = __expf(v[j] - mx); s += v[j]; }
    #pragma unroll
    for (int off = 32; off >= 1; off >>= 1) s += __shfl_xor(s, off);
    if (lane == 0) red_s[wid] = s;
    __syncthreads();
    s = (red_s[0] + red_s[1]) + (red_s[2] + red_s[3]);
    float inv = 1.0f / s;

    u16* pw = (u16*)rp;
    ushort4 u0{ f2bf(v[0] * inv), f2bf(v[1] * inv), f2bf(v[2] * inv), f2bf(v[3] * inv) };
    ushort4 u1{ f2bf(v[4] * inv), f2bf(v[5] * inv), f2bf(v[6] * inv), f2bf(v[7] * inv) };
    reinterpret_cast<ushort4*>(pw)[tid * 2]     = u0;
    reinterpret_cast<ushort4*>(pw)[tid * 2 + 1] = u1;
}

// ---------- launch ----------

extern "C" void kernel_launch(void* const* d_in, const int* in_sizes, int n_in,
                              void* d_out, int out_size, void* d_ws, size_t ws_size,
                              hipStream_t stream) {
    const float* x  = (const float*)d_in[0];
    const float* Wq = (const float*)d_in[1];
    const float* Wk = (const float*)d_in[2];
    const float* Wv = (const float*)d_in[3];

    // ws (MiB) — r4 plan: [0,64) sc f32 | aliased: [0,16) xb, [16,22) Wqkv
    // (both dead before sc is written) | [64,96) qk bf16 [8192][2048] |
    // [96,112) vT bf16 [1024][8192]
    const size_t MiB = 1024 * 1024;
    if (ws_size < 112 * MiB) return;
    char* base = (char*)d_ws;
    float* sc   = (float*)base;
    u16*  xb    = (u16*)base;
    u16*  Wqkvb = (u16*)(base + 16 * MiB);
    u16*  qkb   = (u16*)(base + 64 * MiB);
    u16*  vT    = (u16*)(base + 96 * MiB);

    cvt_all<<<2816, 256, 0, stream>>>(x, Wq, Wk, Wv, xb, Wqkvb);

    // qk = x @ [Wq;Wk]^T : M=8192, N=2048, K=1024 -> bf16 qkb   (grid = 256)
    gemm256<0, 4><<<dim3(8, 32), 512, 0, stream>>>(xb, Wqkvb, qkb, nullptr,
        1024, 1024, 1024, 2048, 31, 0, 1.0f);

    // v = x @ Wv^T, stored transposed -> vT[f][s_global]        (grid = 256)
    gemm256<3, 2><<<dim3(8, 32), 512, 0, stream>>>(xb, Wqkvb + 2097152, nullptr, vT,
        1024, 1024, 1024, 8192, 31, 0, 1.0f);

    // scores = q @ k^T / 32 : M=8192, N=2048, K=1024 -> f32 sc  (grid = 256)
    gemm256<1, 4><<<dim3(8, 32), 512, 0, stream>>>(qkb, qkb + 1024, sc, nullptr,
        1024, 2048, 2048, 2048, 11, (size_t)2048 * 2048, 0.03125f);

    // softmax rows -> bf16 P in place (P lda = 4096 u16)
    softmax_bf16<<<8192, 256, 0, stream>>>(sc);

    // out = P @ vT^T : M=8192, N=1024(f), K=2048(s) -> f32 d_out (grid = 256)
    gemm256<1, 2><<<dim3(8, 32), 512, 0, stream>>>((const u16*)sc, vT, d_out, nullptr,
        2048, 4096, 8192, 1024, 11, 2048, 1.0f);
}